// Round 5
// baseline (448.322 us; speedup 1.0000x reference)
//
#include <hip/hip_runtime.h>
#include <hip/hip_bf16.h>
#include <math.h>

#define NF   128   // F
#define NPH  64    // PH
#define NP   8     // P
#define ND   4     // D
#define NH   128   // H
#define NC   10    // C

typedef __bf16 bf16;
typedef __attribute__((ext_vector_type(4))) __bf16 bf16x4;
typedef __attribute__((ext_vector_type(8))) __bf16 bf16x8;
typedef __attribute__((ext_vector_type(4))) float f32x4;

// fast exact-erf GELU: Abramowitz-Stegun 7.1.25 (3-term), |eps|<=2.5e-5
__device__ __forceinline__ float gelu_fast(float x) {
    float z = fabsf(x) * 0.70710678118654752f;
    float t = 1.0f / (1.0f + 0.47047f * z);
    float poly = t * (0.3480242f + t * (-0.0958798f + t * 0.7478556f));
    float erfv = 1.0f - poly * __expf(-z * z);
    float s = copysignf(erfv, x);
    return 0.5f * x * (1.0f + s);
}

#define GLOAD_LDS16(g, l)                                                     \
    __builtin_amdgcn_global_load_lds(                                         \
        (const __attribute__((address_space(1))) unsigned int*)(g),           \
        (__attribute__((address_space(3))) unsigned int*)(l), 16, 0, 0)

__device__ __forceinline__ bf16x8 cvt8(float4 a, float4 b) {
    bf16x8 r;
    r[0] = (bf16)a.x; r[1] = (bf16)a.y; r[2] = (bf16)a.z; r[3] = (bf16)a.w;
    r[4] = (bf16)b.x; r[5] = (bf16)b.y; r[6] = (bf16)b.z; r[7] = (bf16)b.w;
    return r;
}

// ---------------------------------------------------------------------------
// K1 (MFMA): pp = x@W_proj.T + b_proj (bf16); h = gelu(x@W_x.T + b_x) (f32)
// ---------------------------------------------------------------------------
__global__ __launch_bounds__(256) void k_proj(
    const float* __restrict__ x,
    const float* __restrict__ Wproj, const float* __restrict__ bproj,
    const float* __restrict__ Wx,    const float* __restrict__ bx,
    bf16* __restrict__ pp, float* __restrict__ h, int N)
{
    __shared__ alignas(16) bf16 x_s[64 * 136];
    const int tid = threadIdx.x;
    const int w = tid >> 6, l = tid & 63;
    const int c = l & 15, g = l >> 4;

    bf16x8 bfr[3][4];
    float bias[3];
    #pragma unroll
    for (int t = 0; t < 3; ++t) {
        int ch = (w * 3 + t) * 16 + c;
        const float* wr = (ch < NPH) ? &Wproj[(size_t)ch * NF]
                                     : &Wx[(size_t)(ch - NPH) * NF];
        bias[t] = (ch < NPH) ? bproj[ch] : bx[ch - NPH];
        #pragma unroll
        for (int ks = 0; ks < 4; ++ks) {
            const float* src = wr + ks * 32 + g * 8;
            bfr[t][ks] = cvt8(*(const float4*)src, *(const float4*)(src + 4));
        }
    }

    const int n0 = blockIdx.x * 64;
    #pragma unroll
    for (int rr = 0; rr < 8; ++rr) {
        int id  = rr * 256 + tid;        // 2048 float4 chunks: 64 rows x 32
        int row = id >> 5, c4 = id & 31;
        float4 v = make_float4(0.f, 0.f, 0.f, 0.f);
        if (n0 + row < N) v = *(const float4*)&x[(size_t)(n0 + row) * NF + c4 * 4];
        bf16x4 o;
        o[0] = (bf16)v.x; o[1] = (bf16)v.y; o[2] = (bf16)v.z; o[3] = (bf16)v.w;
        *(bf16x4*)&x_s[row * 136 + c4 * 4] = o;
    }
    __syncthreads();

    f32x4 acc[4][3] = {};
    #pragma unroll
    for (int rt = 0; rt < 4; ++rt)
        #pragma unroll
        for (int ks = 0; ks < 4; ++ks) {
            bf16x8 a = *(const bf16x8*)&x_s[(rt * 16 + c) * 136 + ks * 32 + g * 8];
            #pragma unroll
            for (int t = 0; t < 3; ++t)
                acc[rt][t] = __builtin_amdgcn_mfma_f32_16x16x32_bf16(
                    a, bfr[t][ks], acc[rt][t], 0, 0, 0);
        }

    #pragma unroll
    for (int rt = 0; rt < 4; ++rt) {
        #pragma unroll
        for (int t = 0; t < 3; ++t) {
            int ch = (w * 3 + t) * 16 + c;
            #pragma unroll
            for (int i = 0; i < 4; ++i) {
                int n = n0 + rt * 16 + g * 4 + i;
                if (n >= N) continue;
                float v = acc[rt][t][i] + bias[t];
                if (ch < NPH) pp[(size_t)n * NPH + ch] = (bf16)v;
                else          h[(size_t)n * NH + (ch - NPH)] = gelu_fast(v);
            }
        }
    }
}

// ---------------------------------------------------------------------------
// K2: per round = 2 nodes (16 path rows). Double-buffered, software-pipelined,
// small LDS footprint (18.4 KB) so VGPR (<=102 via launch_bounds) sets the
// occupancy cap at 5 waves/SIMD. All staging address math hoisted to
// per-thread loop invariants; only the index fetch varies per round.
// ---------------------------------------------------------------------------
__global__ __launch_bounds__(256, 5) void k_path(
    const bf16* __restrict__ pp, const float* __restrict__ h,
    const float* __restrict__ Wpath, const float* __restrict__ bpath,
    const int* __restrict__ index, float* __restrict__ aggbuf,
    int N, int nrounds)
{
    __shared__ alignas(16) bf16 path_s[2][16 * 256];  // swizzled content
    __shared__ alignas(16) float h_s[2][2][128];
    __shared__ float s_red[4][16];

    const int tid = threadIdx.x;
    const int w   = tid >> 6;
    const int l   = tid & 63;
    const int c   = l & 15;
    const int g   = l >> 4;
    const int nl  = g >> 1;            // node of this lane's rows (0/1)

    // hoisted staging constants (2 slots/thread: 512 16B chunks = 16 rows x 32)
    const int id0 = tid,        id1 = 256 + tid;
    const int row0 = id0 >> 5,  row1 = id1 >> 5;
    const int ls0 = (id0 & 31) ^ (row0 & 7);
    const int ls1 = (id1 & 31) ^ (row1 & 7);
    const int io0 = (row0 >> 3) * (NP * ND) + (row0 & 7) * ND + (ls0 >> 3);
    const int io1 = (row1 >> 3) * (NP * ND) + (row1 & 7) * ND + (ls1 >> 3);
    const int so0 = (ls0 & 7) * 8, so1 = (ls1 & 7) * 8;
    const int lo0 = id0 * 8,       lo1 = id1 * 8;

    // hoist B fragments (W_path cols for this wave's 2 h-tiles)
    bf16x8 bfrag[2][8];
    #pragma unroll
    for (int ht = 0; ht < 2; ++ht) {
        int hg = (w * 2 + ht) * 16 + c;
        #pragma unroll
        for (int ks = 0; ks < 8; ++ks) {
            const float* src = &Wpath[(size_t)hg * 256 + ks * 32 + g * 8];
            bfrag[ht][ks] = cvt8(*(const float4*)src, *(const float4*)(src + 4));
        }
    }
    const float bp0 = bpath[(w * 2 + 0) * 16 + c];
    const float bp1 = bpath[(w * 2 + 1) * 16 + c];

    auto stage = [&](int round, int b) {
        const int n0 = round * 2;
        const int* ib = index + (size_t)n0 * (NP * ND);
        int idx0 = ib[io0];
        int idx1 = ib[io1];
        GLOAD_LDS16(pp + (size_t)idx0 * NPH + so0, &path_s[b][lo0]);
        GLOAD_LDS16(pp + (size_t)idx1 * NPH + so1, &path_s[b][lo1]);
        if (tid < 64)
            GLOAD_LDS16(&h[(size_t)(n0 + (tid >> 5)) * NH + (tid & 31) * 4],
                        &h_s[b][tid >> 5][(tid & 31) * 4]);
    };

    int r = blockIdx.x;
    const int G = gridDim.x;
    if (r < nrounds) stage(r, 0);
    int buf = 0;

    for (; r < nrounds; r += G) {
        const int n0 = r * 2;
        __syncthreads();                        // round-r stage complete
        if (r + G < nrounds) stage(r + G, buf ^ 1);   // prefetch next round

        // MFMA: 16 rows x this wave's 32 cols
        f32x4 acc0 = {0.f, 0.f, 0.f, 0.f};
        f32x4 acc1 = {0.f, 0.f, 0.f, 0.f};
        const int rowbase = c * 256;
        #pragma unroll
        for (int ks = 0; ks < 8; ++ks) {
            int chunk = (ks * 4 + g) ^ (c & 7);     // read-side XOR
            bf16x8 a = *(const bf16x8*)&path_s[buf][rowbase + chunk * 8];
            acc0 = __builtin_amdgcn_mfma_f32_16x16x32_bf16(a, bfrag[0][ks], acc0, 0, 0, 0);
            acc1 = __builtin_amdgcn_mfma_f32_16x16x32_bf16(a, bfrag[1][ks], acc1, 0, 0, 0);
        }

        // epilogue part 1: pi = gelu(acc+b); partial scores -> s_red
        const float hv0 = h_s[buf][nl][w * 32 + c];
        const float hv1 = h_s[buf][nl][w * 32 + 16 + c];
        float pi0[4], pi1[4], sp[4];
        #pragma unroll
        for (int i = 0; i < 4; ++i) {
            pi0[i] = gelu_fast(acc0[i] + bp0);
            pi1[i] = gelu_fast(acc1[i] + bp1);
            sp[i]  = hv0 * pi0[i] + hv1 * pi1[i];
        }
        #pragma unroll
        for (int off = 1; off < 16; off <<= 1)
            #pragma unroll
            for (int i = 0; i < 4; ++i) sp[i] += __shfl_xor(sp[i], off, 64);
        float v = (c == 0) ? sp[0] : (c == 1) ? sp[1] : (c == 2) ? sp[2] : sp[3];
        if (c < 4) s_red[w][g * 4 + c] = v;

        // raw barrier: drain LDS ops only, keep global_load_lds in flight
        __builtin_amdgcn_sched_barrier(0);
        asm volatile("s_waitcnt lgkmcnt(0)" ::: "memory");
        __builtin_amdgcn_s_barrier();
        __builtin_amdgcn_sched_barrier(0);

        // epilogue part 2: softmax (lane owns 4 rows; partner lane g^1 the rest)
        float st[4];
        #pragma unroll
        for (int i = 0; i < 4; ++i) {
            int row = g * 4 + i;
            st[i] = s_red[0][row] + s_red[1][row] + s_red[2][row] + s_red[3][row];
        }
        float m4 = fmaxf(fmaxf(st[0], st[1]), fmaxf(st[2], st[3]));
        float m  = fmaxf(m4, __shfl_xor(m4, 16, 64));
        float e[4], s4 = 0.f;
        #pragma unroll
        for (int i = 0; i < 4; ++i) { e[i] = __expf(st[i] - m); s4 += e[i]; }
        float den = s4 + __shfl_xor(s4, 16, 64);
        const float inv = 1.0f / den;

        float pa0 = 0.f, pa1 = 0.f;
        #pragma unroll
        for (int i = 0; i < 4; ++i) {
            pa0 += e[i] * pi0[i];
            pa1 += e[i] * pi1[i];
        }
        pa0 = (pa0 + __shfl_xor(pa0, 16, 64)) * inv;
        pa1 = (pa1 + __shfl_xor(pa1, 16, 64)) * inv;

        if (!(g & 1)) {
            int n = n0 + nl;
            aggbuf[(size_t)n * NH + w * 32 + c]      = 0.5f * (pa0 + hv0);
            aggbuf[(size_t)n * NH + w * 32 + 16 + c] = 0.5f * (pa1 + hv1);
        }
        buf ^= 1;
    }
}

// ---------------------------------------------------------------------------
// Edge pipeline v2: bucketed counting sort (bucket = src>>8)
// ---------------------------------------------------------------------------
__global__ __launch_bounds__(256) void k_bhist(
    const int* __restrict__ esrc, int* __restrict__ bcnt, int E, int nbuck)
{
    __shared__ int hist[256];
    hist[threadIdx.x] = 0;
    __syncthreads();
    for (int i = blockIdx.x * 256 + threadIdx.x; i < E; i += gridDim.x * 256)
        atomicAdd(&hist[esrc[i] >> 8], 1);
    __syncthreads();
    if (threadIdx.x < nbuck && hist[threadIdx.x])
        atomicAdd(&bcnt[threadIdx.x], hist[threadIdx.x]);
}

__global__ __launch_bounds__(256) void k_bscan(
    const int* __restrict__ bcnt, int* __restrict__ gbase,
    int* __restrict__ gcur, int nbuck, int E)
{
    __shared__ int s[256];
    const int t = threadIdx.x;
    int v = (t < nbuck) ? bcnt[t] : 0;
    s[t] = v;
    __syncthreads();
    for (int off = 1; off < 256; off <<= 1) {
        int u = (t >= off) ? s[t - off] : 0;
        __syncthreads();
        s[t] += u;
        __syncthreads();
    }
    int ex = s[t] - v;
    if (t < nbuck) { gbase[t] = ex; gcur[t] = ex; }
    if (t == nbuck) gbase[t] = E;
}

__global__ __launch_bounds__(256) void k_bucket(
    const int* __restrict__ esrc, const int* __restrict__ edst,
    int* __restrict__ gcur, uint2* __restrict__ pairs, int E, int nbuck)
{
    __shared__ int cnt[256];
    __shared__ int bofs[256];
    const int tid = threadIdx.x;
    cnt[tid] = 0;
    __syncthreads();

    const int e0 = blockIdx.x * 2048;
    int src[8], dst[8], rk[8];
    #pragma unroll
    for (int k = 0; k < 8; ++k) {
        int i = e0 + k * 256 + tid;
        if (i < E) {
            src[k] = esrc[i]; dst[k] = edst[i];
            rk[k]  = atomicAdd(&cnt[src[k] >> 8], 1);
        } else src[k] = -1;
    }
    __syncthreads();
    if (tid < nbuck) {
        int cc = cnt[tid];
        bofs[tid] = cc ? atomicAdd(&gcur[tid], cc) : 0;
    }
    __syncthreads();
    #pragma unroll
    for (int k = 0; k < 8; ++k)
        if (src[k] >= 0)
            pairs[bofs[src[k] >> 8] + rk[k]] =
                make_uint2((unsigned)src[k], (unsigned)dst[k]);
}

__global__ __launch_bounds__(256) void k_bsort(
    const uint2* __restrict__ pairs, const int* __restrict__ gbase,
    int* __restrict__ sdst, int* __restrict__ base, int N, int E)
{
    __shared__ int hist[256], sc[256], cur[256];
    const int b = blockIdx.x, t = threadIdx.x;
    const int lo = gbase[b], hi = gbase[b + 1];
    hist[t] = 0;
    __syncthreads();
    for (int j = lo + t; j < hi; j += 256)
        atomicAdd(&hist[pairs[j].x & 255], 1);
    __syncthreads();
    int v = hist[t];
    sc[t] = v;
    __syncthreads();
    for (int off = 1; off < 256; off <<= 1) {
        int u = (t >= off) ? sc[t - off] : 0;
        __syncthreads();
        sc[t] += u;
        __syncthreads();
    }
    int ex = lo + sc[t] - v;
    cur[t] = ex;
    int n = b * 256 + t;
    if (n < N) base[n] = ex;
    if (b == 0 && t == 0) base[N] = E;
    __syncthreads();
    for (int j = lo + t; j < hi; j += 256) {
        uint2 p = pairs[j];
        int pos = atomicAdd(&cur[p.x & 255], 1);
        sdst[pos] = (int)p.y;
    }
}

// ---------------------------------------------------------------------------
// Transpose W_A [H,N] f32 -> M [N,H] bf16
// ---------------------------------------------------------------------------
__global__ __launch_bounds__(256) void k_transpose(
    const float* __restrict__ WA, bf16* __restrict__ M, int N)
{
    __shared__ float t[128][65];
    const int n0  = blockIdx.x * 64;
    const int tid = threadIdx.x;
    const int w = tid >> 6, l = tid & 63;
    #pragma unroll
    for (int rep = 0; rep < 32; ++rep) {
        int hh = rep * 4 + w;
        int n  = n0 + l;
        t[hh][l] = (n < N) ? WA[(size_t)hh * N + n] : 0.f;
    }
    __syncthreads();
    #pragma unroll
    for (int rep = 0; rep < 32; ++rep) {
        int n_l = rep * 2 + (tid >> 7);
        int n   = n0 + n_l;
        if (n < N) M[(size_t)n * NH + (tid & 127)] = (bf16)t[tid & 127][n_l];
    }
}

// ---------------------------------------------------------------------------
// K3: A_x row-gather + fused finale. One wave per node; 16-lane x 8-edge
// dwordx4 gathers -> 8 outstanding 256B rows per wave (32 edges/iter).
// ---------------------------------------------------------------------------
__device__ __forceinline__ void add8(float* a, uint4 v) {
    a[0] += __uint_as_float(v.x << 16);  a[1] += __uint_as_float(v.x & 0xffff0000u);
    a[2] += __uint_as_float(v.y << 16);  a[3] += __uint_as_float(v.y & 0xffff0000u);
    a[4] += __uint_as_float(v.z << 16);  a[5] += __uint_as_float(v.z & 0xffff0000u);
    a[6] += __uint_as_float(v.w << 16);  a[7] += __uint_as_float(v.w & 0xffff0000u);
}

__global__ __launch_bounds__(256) void k_spmm_out(
    const bf16* __restrict__ Mb, const int* __restrict__ base,
    const int* __restrict__ sdst, const float* __restrict__ aggbuf,
    const float* __restrict__ bA, const float* __restrict__ Wend,
    const float* __restrict__ bend, float* __restrict__ out, int N)
{
    __shared__ float wend_s[NC][128];
    __shared__ float bend_s[NC];
    const int tid = threadIdx.x;
    for (int id = tid; id < NC * 128; id += 256) wend_s[id >> 7][id & 127] = Wend[id];
    if (tid < NC) bend_s[tid] = bend[tid];
    __syncthreads();

    const int w = tid >> 6, l = tid & 63;
    const int n = blockIdx.x * 4 + w;
    if (n >= N) return;
    const int e = l >> 4, q = l & 15;
    const unsigned short* Mu = (const unsigned short*)Mb;

    const int b0 = base[n], b1 = base[n + 1];
    float acc[8] = {0.f, 0.f, 0.f, 0.f, 0.f, 0.f, 0.f, 0.f};
    int j = b0;
    for (; j + 32 <= b1; j += 32) {
        int d[8];
        #pragma unroll
        for (int k = 0; k < 8; ++k) d[k] = sdst[j + k * 4 + e];
        uint4 v[8];
        #pragma unroll
        for (int k = 0; k < 8; ++k)
            v[k] = *((const uint4*)(Mu + (size_t)d[k] * NH) + q);
        #pragma unroll
        for (int k = 0; k < 8; ++k) add8(acc, v[k]);
    }
    for (; j + 16 <= b1; j += 16) {
        int d[4];
        #pragma unroll
        for (int k = 0; k < 4; ++k) d[k] = sdst[j + k * 4 + e];
        uint4 v[4];
        #pragma unroll
        for (int k = 0; k < 4; ++k)
            v[k] = *((const uint4*)(Mu + (size_t)d[k] * NH) + q);
        #pragma unroll
        for (int k = 0; k < 4; ++k) add8(acc, v[k]);
    }
    for (; j + 4 <= b1; j += 4) {
        int d0 = sdst[j + e];
        uint4 v0 = *((const uint4*)(Mu + (size_t)d0 * NH) + q);
        add8(acc, v0);
    }
    if (e < b1 - j) {
        int d0 = sdst[j + e];
        uint4 v0 = *((const uint4*)(Mu + (size_t)d0 * NH) + q);
        add8(acc, v0);
    }
    #pragma unroll
    for (int k = 0; k < 8; ++k) {
        acc[k] += __shfl_xor(acc[k], 16, 64);
        acc[k] += __shfl_xor(acc[k], 32, 64);
    }

    // epilogue: all lanes (4x redundant across e-groups), lane owns ch q*8..+7
    float4 agA = *(const float4*)&aggbuf[(size_t)n * NH + q * 8];
    float4 agB = *(const float4*)&aggbuf[(size_t)n * NH + q * 8 + 4];
    float4 bA0 = *(const float4*)&bA[q * 8];
    float4 bA1 = *(const float4*)&bA[q * 8 + 4];
    float gg[8];
    gg[0] = gelu_fast(agA.x + 0.5f * (acc[0] + bA0.x));
    gg[1] = gelu_fast(agA.y + 0.5f * (acc[1] + bA0.y));
    gg[2] = gelu_fast(agA.z + 0.5f * (acc[2] + bA0.z));
    gg[3] = gelu_fast(agA.w + 0.5f * (acc[3] + bA0.w));
    gg[4] = gelu_fast(agB.x + 0.5f * (acc[4] + bA1.x));
    gg[5] = gelu_fast(agB.y + 0.5f * (acc[5] + bA1.y));
    gg[6] = gelu_fast(agB.z + 0.5f * (acc[6] + bA1.z));
    gg[7] = gelu_fast(agB.w + 0.5f * (acc[7] + bA1.w));

    float part[NC];
    #pragma unroll
    for (int cc = 0; cc < NC; ++cc) {
        float p = 0.f;
        #pragma unroll
        for (int k = 0; k < 8; ++k) p += gg[k] * wend_s[cc][q * 8 + k];
        part[cc] = p;
    }
    #pragma unroll
    for (int off = 1; off < 16; off <<= 1)
        #pragma unroll
        for (int cc = 0; cc < NC; ++cc) part[cc] += __shfl_xor(part[cc], off, 64);

    float r = part[0];
    #pragma unroll
    for (int cc = 1; cc < NC; ++cc) r = (l == cc) ? part[cc] : r;
    if (l < NC) out[(size_t)n * NC + l] = r + bend_s[l];
}

// ---------------------------------------------------------------------------
extern "C" void kernel_launch(void* const* d_in, const int* in_sizes, int n_in,
                              void* d_out, int out_size, void* d_ws, size_t ws_size,
                              hipStream_t stream)
{
    const float* x     = (const float*)d_in[0];
    const float* Wproj = (const float*)d_in[1];
    const float* bproj = (const float*)d_in[2];
    const float* Wx    = (const float*)d_in[3];
    const float* bx    = (const float*)d_in[4];
    const float* Wpath = (const float*)d_in[5];
    const float* bpath = (const float*)d_in[6];
    const float* WA    = (const float*)d_in[7];
    const float* bA    = (const float*)d_in[8];
    const float* Wend  = (const float*)d_in[9];
    const float* bend  = (const float*)d_in[10];
    const int*   index = (const int*)d_in[11];
    const int*   eidx  = (const int*)d_in[12];

    const int N = in_sizes[0] / NF;
    const int E = in_sizes[12] / 2;
    const int* esrc = eidx;
    const int* edst = eidx + E;
    const int nbuck = (N + 255) >> 8;

    char* p = (char*)d_ws;
    auto alloc = [&](size_t bytes) {
        char* r = p;
        p += (bytes + 255) & ~(size_t)255;
        return r;
    };
    bf16*  pp     = (bf16*)alloc((size_t)N * NPH * sizeof(bf16));
    float* h      = (float*)alloc((size_t)N * NH * sizeof(float));
    float* aggbuf = (float*)alloc((size_t)N * NH * sizeof(float));
    bf16*  Mb     = (bf16*)alloc((size_t)N * NH * sizeof(bf16));
    int*   base   = (int*)alloc((size_t)(N + 1) * sizeof(int));
    int*   sdst   = (int*)alloc((size_t)E * sizeof(int));
    int*   bcnt   = (int*)alloc(256 * sizeof(int));
    int*   gbase  = (int*)alloc(257 * sizeof(int));
    int*   gcur   = (int*)alloc(256 * sizeof(int));
    uint2* pairs  = (uint2*)alloc((size_t)E * sizeof(uint2));

    hipMemsetAsync(bcnt, 0, 256 * sizeof(int), stream);
    k_bhist<<<256, 256, 0, stream>>>(esrc, bcnt, E, nbuck);
    k_bscan<<<1, 256, 0, stream>>>(bcnt, gbase, gcur, nbuck, E);
    k_bucket<<<(E + 2047) / 2048, 256, 0, stream>>>(esrc, edst, gcur, pairs, E, nbuck);
    k_bsort<<<nbuck, 256, 0, stream>>>(pairs, gbase, sdst, base, N, E);
    k_transpose<<<(N + 63) / 64, 256, 0, stream>>>(WA, Mb, N);
    k_proj<<<(N + 63) / 64, 256, 0, stream>>>(x, Wproj, bproj, Wx, bx, pp, h, N);
    const int nrounds = N / 2;
    k_path<<<2048, 256, 0, stream>>>(pp, h, Wpath, bpath, index, aggbuf, N, nrounds);
    k_spmm_out<<<(N + 3) / 4, 256, 0, stream>>>(Mb, base, sdst, aggbuf, bA, Wend, bend,
                                                (float*)d_out, N);
}

// Round 6
// 273.187 us; speedup vs baseline: 1.6411x; 1.6411x over previous
//
#include <hip/hip_runtime.h>
#include <hip/hip_bf16.h>
#include <math.h>

#define NF   128   // F
#define NPH  64    // PH
#define NP   8     // P
#define ND   4     // D
#define NH   128   // H
#define NC   10    // C

typedef __bf16 bf16;
typedef __attribute__((ext_vector_type(4))) __bf16 bf16x4;
typedef __attribute__((ext_vector_type(8))) __bf16 bf16x8;
typedef __attribute__((ext_vector_type(4))) float f32x4;

// fast exact-erf GELU: Abramowitz-Stegun 7.1.25 (3-term), |eps|<=2.5e-5
__device__ __forceinline__ float gelu_fast(float x) {
    float z = fabsf(x) * 0.70710678118654752f;
    float t = 1.0f / (1.0f + 0.47047f * z);
    float poly = t * (0.3480242f + t * (-0.0958798f + t * 0.7478556f));
    float erfv = 1.0f - poly * __expf(-z * z);
    float s = copysignf(erfv, x);
    return 0.5f * x * (1.0f + s);
}

#define GLOAD_LDS16(g, l)                                                     \
    __builtin_amdgcn_global_load_lds(                                         \
        (const __attribute__((address_space(1))) unsigned int*)(g),           \
        (__attribute__((address_space(3))) unsigned int*)(l), 16, 0, 0)

__device__ __forceinline__ bf16x8 cvt8(float4 a, float4 b) {
    bf16x8 r;
    r[0] = (bf16)a.x; r[1] = (bf16)a.y; r[2] = (bf16)a.z; r[3] = (bf16)a.w;
    r[4] = (bf16)b.x; r[5] = (bf16)b.y; r[6] = (bf16)b.z; r[7] = (bf16)b.w;
    return r;
}

// ---------------------------------------------------------------------------
// k_front: fused [proj | transpose | bhist] — mutually independent stages.
//   proj     : pp = x@W_proj.T + b_proj (bf16); h = gelu(x@W_x.T + b_x)
//   transpose: W_A [H,N] f32 -> Mb [N,H] bf16
//   bhist    : bucket histogram of esrc>>8
// LDS: one char arena, per-branch views (max user = transpose, 33280 B).
// ---------------------------------------------------------------------------
#define NBH 256   // bhist block count

__global__ __launch_bounds__(256) void k_front(
    const float* __restrict__ x,
    const float* __restrict__ Wproj, const float* __restrict__ bproj,
    const float* __restrict__ Wx,    const float* __restrict__ bx,
    bf16* __restrict__ pp, float* __restrict__ h,
    const float* __restrict__ WA, bf16* __restrict__ Mb,
    const int* __restrict__ esrc, int* __restrict__ bcnt,
    int N, int E, int nbuck, int nbP, int nbT)
{
    __shared__ alignas(16) char smem[33280];
    const int tid = threadIdx.x;
    const int bid = blockIdx.x;

    if (bid < nbP) {
        // ---------------- proj ----------------
        bf16* x_s = (bf16*)smem;                 // [64][136]
        const int w = tid >> 6, l = tid & 63;
        const int c = l & 15, g = l >> 4;

        bf16x8 bfr[3][4];
        float bias[3];
        #pragma unroll
        for (int t = 0; t < 3; ++t) {
            int ch = (w * 3 + t) * 16 + c;
            const float* wr = (ch < NPH) ? &Wproj[(size_t)ch * NF]
                                         : &Wx[(size_t)(ch - NPH) * NF];
            bias[t] = (ch < NPH) ? bproj[ch] : bx[ch - NPH];
            #pragma unroll
            for (int ks = 0; ks < 4; ++ks) {
                const float* src = wr + ks * 32 + g * 8;
                bfr[t][ks] = cvt8(*(const float4*)src, *(const float4*)(src + 4));
            }
        }

        const int n0 = bid * 64;
        #pragma unroll
        for (int rr = 0; rr < 8; ++rr) {
            int id  = rr * 256 + tid;        // 2048 float4 chunks: 64 rows x 32
            int row = id >> 5, c4 = id & 31;
            float4 v = make_float4(0.f, 0.f, 0.f, 0.f);
            if (n0 + row < N) v = *(const float4*)&x[(size_t)(n0 + row) * NF + c4 * 4];
            bf16x4 o;
            o[0] = (bf16)v.x; o[1] = (bf16)v.y; o[2] = (bf16)v.z; o[3] = (bf16)v.w;
            *(bf16x4*)&x_s[row * 136 + c4 * 4] = o;
        }
        __syncthreads();

        f32x4 acc[4][3] = {};
        #pragma unroll
        for (int rt = 0; rt < 4; ++rt)
            #pragma unroll
            for (int ks = 0; ks < 4; ++ks) {
                bf16x8 a = *(const bf16x8*)&x_s[(rt * 16 + c) * 136 + ks * 32 + g * 8];
                #pragma unroll
                for (int t = 0; t < 3; ++t)
                    acc[rt][t] = __builtin_amdgcn_mfma_f32_16x16x32_bf16(
                        a, bfr[t][ks], acc[rt][t], 0, 0, 0);
            }

        #pragma unroll
        for (int rt = 0; rt < 4; ++rt) {
            #pragma unroll
            for (int t = 0; t < 3; ++t) {
                int ch = (w * 3 + t) * 16 + c;
                #pragma unroll
                for (int i = 0; i < 4; ++i) {
                    int n = n0 + rt * 16 + g * 4 + i;
                    if (n >= N) continue;
                    float v = acc[rt][t][i] + bias[t];
                    if (ch < NPH) pp[(size_t)n * NPH + ch] = (bf16)v;
                    else          h[(size_t)n * NH + (ch - NPH)] = gelu_fast(v);
                }
            }
        }
    } else if (bid < nbP + nbT) {
        // ---------------- transpose ----------------
        float* tt = (float*)smem;                // [128][65]
        const int n0 = (bid - nbP) * 64;
        const int w = tid >> 6, l = tid & 63;
        #pragma unroll
        for (int rep = 0; rep < 32; ++rep) {
            int hh = rep * 4 + w;
            int n  = n0 + l;
            tt[hh * 65 + l] = (n < N) ? WA[(size_t)hh * N + n] : 0.f;
        }
        __syncthreads();
        #pragma unroll
        for (int rep = 0; rep < 32; ++rep) {
            int n_l = rep * 2 + (tid >> 7);
            int n   = n0 + n_l;
            if (n < N) Mb[(size_t)n * NH + (tid & 127)] = (bf16)tt[(tid & 127) * 65 + n_l];
        }
    } else {
        // ---------------- bhist ----------------
        int* hist = (int*)smem;
        hist[tid] = 0;
        __syncthreads();
        const int hb = bid - nbP - nbT;
        for (int i = hb * 256 + tid; i < E; i += NBH * 256)
            atomicAdd(&hist[esrc[i] >> 8], 1);
        __syncthreads();
        if (tid < nbuck && hist[tid])
            atomicAdd(&bcnt[tid], hist[tid]);
    }
}

// ---------------------------------------------------------------------------
__global__ __launch_bounds__(256) void k_bscan(
    const int* __restrict__ bcnt, int* __restrict__ gbase,
    int* __restrict__ gcur, int nbuck, int E)
{
    __shared__ int s[256];
    const int t = threadIdx.x;
    int v = (t < nbuck) ? bcnt[t] : 0;
    s[t] = v;
    __syncthreads();
    for (int off = 1; off < 256; off <<= 1) {
        int u = (t >= off) ? s[t - off] : 0;
        __syncthreads();
        s[t] += u;
        __syncthreads();
    }
    int ex = s[t] - v;
    if (t < nbuck) { gbase[t] = ex; gcur[t] = ex; }
    if (t == nbuck) gbase[t] = E;
}

__global__ __launch_bounds__(256) void k_bucket(
    const int* __restrict__ esrc, const int* __restrict__ edst,
    int* __restrict__ gcur, uint2* __restrict__ pairs, int E, int nbuck)
{
    __shared__ int cnt[256];
    __shared__ int bofs[256];
    const int tid = threadIdx.x;
    cnt[tid] = 0;
    __syncthreads();

    const int e0 = blockIdx.x * 2048;
    int src[8], dst[8], rk[8];
    #pragma unroll
    for (int k = 0; k < 8; ++k) {
        int i = e0 + k * 256 + tid;
        if (i < E) {
            src[k] = esrc[i]; dst[k] = edst[i];
            rk[k]  = atomicAdd(&cnt[src[k] >> 8], 1);
        } else src[k] = -1;
    }
    __syncthreads();
    if (tid < nbuck) {
        int cc = cnt[tid];
        bofs[tid] = cc ? atomicAdd(&gcur[tid], cc) : 0;
    }
    __syncthreads();
    #pragma unroll
    for (int k = 0; k < 8; ++k)
        if (src[k] >= 0)
            pairs[bofs[src[k] >> 8] + rk[k]] =
                make_uint2((unsigned)src[k], (unsigned)dst[k]);
}

// ---------------------------------------------------------------------------
// k_mid: fused [bsort | path].
//   bsort blocks (bid < nbuck): per-bucket sort -> base[], sdst
//   path blocks : round-4 proven k_path (4 nodes/round, dbuf, pipelined)
// LDS arena: path view 37376 B; bsort view 3072 B.
// ---------------------------------------------------------------------------
__global__ __launch_bounds__(256) void k_mid(
    const uint2* __restrict__ pairs, const int* __restrict__ gbase,
    int* __restrict__ sdst, int* __restrict__ base,
    const bf16* __restrict__ pp, const float* __restrict__ h,
    const float* __restrict__ Wpath, const float* __restrict__ bpath,
    const int* __restrict__ index, float* __restrict__ aggbuf,
    int N, int E, int nbuck, int nrounds)
{
    __shared__ alignas(16) char smem[37376];
    const int tid = threadIdx.x;

    if (blockIdx.x < nbuck) {
        // ---------------- bsort ----------------
        int* hist = (int*)smem;
        int* sc   = hist + 256;
        int* cur  = hist + 512;
        const int b = blockIdx.x, t = tid;
        const int lo = gbase[b], hi = gbase[b + 1];
        hist[t] = 0;
        __syncthreads();
        for (int j = lo + t; j < hi; j += 256)
            atomicAdd(&hist[pairs[j].x & 255], 1);
        __syncthreads();
        int v = hist[t];
        sc[t] = v;
        __syncthreads();
        for (int off = 1; off < 256; off <<= 1) {
            int u = (t >= off) ? sc[t - off] : 0;
            __syncthreads();
            sc[t] += u;
            __syncthreads();
        }
        int ex = lo + sc[t] - v;
        cur[t] = ex;
        int n = b * 256 + t;
        if (n < N) base[n] = ex;
        if (b == 0 && t == 0) base[N] = E;
        __syncthreads();
        for (int j = lo + t; j < hi; j += 256) {
            uint2 p = pairs[j];
            int pos = atomicAdd(&cur[p.x & 255], 1);
            sdst[pos] = (int)p.y;
        }
        return;
    }

    // ---------------- path (round-4 structure) ----------------
    bf16*  path_s = (bf16*)smem;                 // [2][32*256]
    float* h_sf   = (float*)(smem + 32768);      // [2][4][128]
    float* s_red  = (float*)(smem + 36864);      // [4][32]

    const int w   = tid >> 6;
    const int l   = tid & 63;
    const int c   = l & 15;
    const int g   = l >> 4;
    const int nl  = g >> 1;            // local node (within a pair)

    // hoist B fragments (W_path cols for this wave's 2 h-tiles)
    bf16x8 bfrag[2][8];
    #pragma unroll
    for (int ht = 0; ht < 2; ++ht) {
        int hg = (w * 2 + ht) * 16 + c;
        #pragma unroll
        for (int ks = 0; ks < 8; ++ks) {
            const float* src = &Wpath[(size_t)hg * 256 + ks * 32 + g * 8];
            bfrag[ht][ks] = cvt8(*(const float4*)src, *(const float4*)(src + 4));
        }
    }
    const float bp0 = bpath[(w * 2 + 0) * 16 + c];
    const float bp1 = bpath[(w * 2 + 1) * 16 + c];

    auto stage = [&](int round, int b) {
        const int n0 = round * 4;
        #pragma unroll
        for (int rr = 0; rr < 4; ++rr) {
            int id  = rr * 256 + tid;
            int row = id >> 5;
            int cc  = id & 31;
            int ls  = cc ^ (row & 7);      // source-side swizzle
            int d   = ls >> 3, q = ls & 7;
            int nn  = row >> 3, p = row & 7;
            int idx = index[(size_t)(n0 + nn) * (NP * ND) + p * ND + d];
            GLOAD_LDS16(pp + (size_t)idx * NPH + q * 8, &path_s[b * 8192 + id * 8]);
        }
        if (tid < 128) {
            int node = tid >> 5, q = tid & 31;
            GLOAD_LDS16(&h[(size_t)(n0 + node) * NH + q * 4],
                        &h_sf[(b * 4 + node) * 128 + q * 4]);
        }
    };

    int r = blockIdx.x - nbuck;
    const int G = gridDim.x - nbuck;
    if (r < nrounds) stage(r, 0);
    int buf = 0;

    for (; r < nrounds; r += G) {
        const int n0 = r * 4;
        __syncthreads();                        // round-r stage complete
        if (r + G < nrounds) stage(r + G, buf ^ 1);   // prefetch next round

        // MFMA: row-tile rt covers rows rt*16..rt*16+15 (pair rt)
        f32x4 acc[2][2] = {};
        #pragma unroll
        for (int rt = 0; rt < 2; ++rt) {
            const int rowbase = buf * 8192 + (rt * 16 + c) * 256;
            #pragma unroll
            for (int ks = 0; ks < 8; ++ks) {
                int chunk = (ks * 4 + g) ^ (c & 7);     // read-side XOR
                bf16x8 a = *(const bf16x8*)&path_s[rowbase + chunk * 8];
                acc[rt][0] = __builtin_amdgcn_mfma_f32_16x16x32_bf16(
                    a, bfrag[0][ks], acc[rt][0], 0, 0, 0);
                acc[rt][1] = __builtin_amdgcn_mfma_f32_16x16x32_bf16(
                    a, bfrag[1][ks], acc[rt][1], 0, 0, 0);
            }
        }

        // epilogue part 1: pi = gelu(acc+b); partial scores -> s_red
        float pi[2][2][4];
        #pragma unroll
        for (int rt = 0; rt < 2; ++rt) {
            const float hv0 = h_sf[(buf * 4 + rt * 2 + nl) * 128 + w * 32 + c];
            const float hv1 = h_sf[(buf * 4 + rt * 2 + nl) * 128 + w * 32 + 16 + c];
            float sp[4];
            #pragma unroll
            for (int i = 0; i < 4; ++i) {
                pi[rt][0][i] = gelu_fast(acc[rt][0][i] + bp0);
                pi[rt][1][i] = gelu_fast(acc[rt][1][i] + bp1);
                sp[i] = hv0 * pi[rt][0][i] + hv1 * pi[rt][1][i];
            }
            #pragma unroll
            for (int off = 1; off < 16; off <<= 1)
                #pragma unroll
                for (int i = 0; i < 4; ++i) sp[i] += __shfl_xor(sp[i], off, 64);
            float v = (c == 0) ? sp[0] : (c == 1) ? sp[1] : (c == 2) ? sp[2] : sp[3];
            if (c < 4) s_red[w * 32 + rt * 16 + g * 4 + c] = v;
        }

        // raw barrier: drain LDS ops only, keep global_load_lds in flight
        __builtin_amdgcn_sched_barrier(0);
        asm volatile("s_waitcnt lgkmcnt(0)" ::: "memory");
        __builtin_amdgcn_s_barrier();
        __builtin_amdgcn_sched_barrier(0);

        // epilogue part 2: softmax (lane computes its own 4 rows + partner)
        #pragma unroll
        for (int rt = 0; rt < 2; ++rt) {
            float st[4];
            #pragma unroll
            for (int i = 0; i < 4; ++i) {
                int row = rt * 16 + g * 4 + i;
                st[i] = s_red[0 * 32 + row] + s_red[1 * 32 + row] +
                        s_red[2 * 32 + row] + s_red[3 * 32 + row];
            }
            float m4 = fmaxf(fmaxf(st[0], st[1]), fmaxf(st[2], st[3]));
            float m  = fmaxf(m4, __shfl_xor(m4, 16, 64));
            float e[4], s4 = 0.f;
            #pragma unroll
            for (int i = 0; i < 4; ++i) { e[i] = __expf(st[i] - m); s4 += e[i]; }
            float den = s4 + __shfl_xor(s4, 16, 64);
            const float inv = 1.0f / den;

            float pa0 = 0.f, pa1 = 0.f;
            #pragma unroll
            for (int i = 0; i < 4; ++i) {
                pa0 += e[i] * pi[rt][0][i];
                pa1 += e[i] * pi[rt][1][i];
            }
            pa0 = (pa0 + __shfl_xor(pa0, 16, 64)) * inv;
            pa1 = (pa1 + __shfl_xor(pa1, 16, 64)) * inv;

            if (!(g & 1)) {
                int n = n0 + rt * 2 + nl;
                const float hv0 = h_sf[(buf * 4 + rt * 2 + nl) * 128 + w * 32 + c];
                const float hv1 = h_sf[(buf * 4 + rt * 2 + nl) * 128 + w * 32 + 16 + c];
                aggbuf[(size_t)n * NH + w * 32 + c]      = 0.5f * (pa0 + hv0);
                aggbuf[(size_t)n * NH + w * 32 + 16 + c] = 0.5f * (pa1 + hv1);
            }
        }
        buf ^= 1;
    }
}

// ---------------------------------------------------------------------------
// K3: A_x row-gather + fused finale. One wave per node; 16-lane x 8-edge
// dwordx4 gathers -> 8 outstanding 256B rows per wave (32 edges/iter).
// ---------------------------------------------------------------------------
__device__ __forceinline__ void add8(float* a, uint4 v) {
    a[0] += __uint_as_float(v.x << 16);  a[1] += __uint_as_float(v.x & 0xffff0000u);
    a[2] += __uint_as_float(v.y << 16);  a[3] += __uint_as_float(v.y & 0xffff0000u);
    a[4] += __uint_as_float(v.z << 16);  a[5] += __uint_as_float(v.z & 0xffff0000u);
    a[6] += __uint_as_float(v.w << 16);  a[7] += __uint_as_float(v.w & 0xffff0000u);
}

__global__ __launch_bounds__(256) void k_spmm_out(
    const bf16* __restrict__ Mb, const int* __restrict__ base,
    const int* __restrict__ sdst, const float* __restrict__ aggbuf,
    const float* __restrict__ bA, const float* __restrict__ Wend,
    const float* __restrict__ bend, float* __restrict__ out, int N)
{
    __shared__ float wend_s[NC][128];
    __shared__ float bend_s[NC];
    const int tid = threadIdx.x;
    for (int id = tid; id < NC * 128; id += 256) wend_s[id >> 7][id & 127] = Wend[id];
    if (tid < NC) bend_s[tid] = bend[tid];
    __syncthreads();

    const int w = tid >> 6, l = tid & 63;
    const int n = blockIdx.x * 4 + w;
    if (n >= N) return;
    const int e = l >> 4, q = l & 15;
    const unsigned short* Mu = (const unsigned short*)Mb;

    const int b0 = base[n], b1 = base[n + 1];
    float acc[8] = {0.f, 0.f, 0.f, 0.f, 0.f, 0.f, 0.f, 0.f};
    int j = b0;
    for (; j + 32 <= b1; j += 32) {
        int d[8];
        #pragma unroll
        for (int k = 0; k < 8; ++k) d[k] = sdst[j + k * 4 + e];
        uint4 v[8];
        #pragma unroll
        for (int k = 0; k < 8; ++k)
            v[k] = *((const uint4*)(Mu + (size_t)d[k] * NH) + q);
        #pragma unroll
        for (int k = 0; k < 8; ++k) add8(acc, v[k]);
    }
    for (; j + 16 <= b1; j += 16) {
        int d[4];
        #pragma unroll
        for (int k = 0; k < 4; ++k) d[k] = sdst[j + k * 4 + e];
        uint4 v[4];
        #pragma unroll
        for (int k = 0; k < 4; ++k)
            v[k] = *((const uint4*)(Mu + (size_t)d[k] * NH) + q);
        #pragma unroll
        for (int k = 0; k < 4; ++k) add8(acc, v[k]);
    }
    for (; j + 4 <= b1; j += 4) {
        int d0 = sdst[j + e];
        uint4 v0 = *((const uint4*)(Mu + (size_t)d0 * NH) + q);
        add8(acc, v0);
    }
    if (e < b1 - j) {
        int d0 = sdst[j + e];
        uint4 v0 = *((const uint4*)(Mu + (size_t)d0 * NH) + q);
        add8(acc, v0);
    }
    #pragma unroll
    for (int k = 0; k < 8; ++k) {
        acc[k] += __shfl_xor(acc[k], 16, 64);
        acc[k] += __shfl_xor(acc[k], 32, 64);
    }

    // epilogue: all lanes (4x redundant across e-groups), lane owns ch q*8..+7
    float4 agA = *(const float4*)&aggbuf[(size_t)n * NH + q * 8];
    float4 agB = *(const float4*)&aggbuf[(size_t)n * NH + q * 8 + 4];
    float4 bA0 = *(const float4*)&bA[q * 8];
    float4 bA1 = *(const float4*)&bA[q * 8 + 4];
    float gg[8];
    gg[0] = gelu_fast(agA.x + 0.5f * (acc[0] + bA0.x));
    gg[1] = gelu_fast(agA.y + 0.5f * (acc[1] + bA0.y));
    gg[2] = gelu_fast(agA.z + 0.5f * (acc[2] + bA0.z));
    gg[3] = gelu_fast(agA.w + 0.5f * (acc[3] + bA0.w));
    gg[4] = gelu_fast(agB.x + 0.5f * (acc[4] + bA1.x));
    gg[5] = gelu_fast(agB.y + 0.5f * (acc[5] + bA1.y));
    gg[6] = gelu_fast(agB.z + 0.5f * (acc[6] + bA1.z));
    gg[7] = gelu_fast(agB.w + 0.5f * (acc[7] + bA1.w));

    float part[NC];
    #pragma unroll
    for (int cc = 0; cc < NC; ++cc) {
        float p = 0.f;
        #pragma unroll
        for (int k = 0; k < 8; ++k) p += gg[k] * wend_s[cc][q * 8 + k];
        part[cc] = p;
    }
    #pragma unroll
    for (int off = 1; off < 16; off <<= 1)
        #pragma unroll
        for (int cc = 0; cc < NC; ++cc) part[cc] += __shfl_xor(part[cc], off, 64);

    float r = part[0];
    #pragma unroll
    for (int cc = 1; cc < NC; ++cc) r = (l == cc) ? part[cc] : r;
    if (l < NC) out[(size_t)n * NC + l] = r + bend_s[l];
}

// ---------------------------------------------------------------------------
extern "C" void kernel_launch(void* const* d_in, const int* in_sizes, int n_in,
                              void* d_out, int out_size, void* d_ws, size_t ws_size,
                              hipStream_t stream)
{
    const float* x     = (const float*)d_in[0];
    const float* Wproj = (const float*)d_in[1];
    const float* bproj = (const float*)d_in[2];
    const float* Wx    = (const float*)d_in[3];
    const float* bx    = (const float*)d_in[4];
    const float* Wpath = (const float*)d_in[5];
    const float* bpath = (const float*)d_in[6];
    const float* WA    = (const float*)d_in[7];
    const float* bA    = (const float*)d_in[8];
    const float* Wend  = (const float*)d_in[9];
    const float* bend  = (const float*)d_in[10];
    const int*   index = (const int*)d_in[11];
    const int*   eidx  = (const int*)d_in[12];

    const int N = in_sizes[0] / NF;
    const int E = in_sizes[12] / 2;
    const int* esrc = eidx;
    const int* edst = eidx + E;
    const int nbuck = (N + 255) >> 8;

    char* p = (char*)d_ws;
    auto alloc = [&](size_t bytes) {
        char* r = p;
        p += (bytes + 255) & ~(size_t)255;
        return r;
    };
    bf16*  pp     = (bf16*)alloc((size_t)N * NPH * sizeof(bf16));
    float* h      = (float*)alloc((size_t)N * NH * sizeof(float));
    float* aggbuf = (float*)alloc((size_t)N * NH * sizeof(float));
    bf16*  Mb     = (bf16*)alloc((size_t)N * NH * sizeof(bf16));
    int*   base   = (int*)alloc((size_t)(N + 1) * sizeof(int));
    int*   sdst   = (int*)alloc((size_t)E * sizeof(int));
    int*   bcnt   = (int*)alloc(256 * sizeof(int));
    int*   gbase  = (int*)alloc(257 * sizeof(int));
    int*   gcur   = (int*)alloc(256 * sizeof(int));
    uint2* pairs  = (uint2*)alloc((size_t)E * sizeof(uint2));

    const int nbP = (N + 63) / 64;
    const int nbT = (N + 63) / 64;
    const int NPATH = 1024;
    const int nrounds = N / 4;

    hipMemsetAsync(bcnt, 0, 256 * sizeof(int), stream);
    k_front<<<nbP + nbT + NBH, 256, 0, stream>>>(
        x, Wproj, bproj, Wx, bx, pp, h, WA, Mb, esrc, bcnt, N, E, nbuck, nbP, nbT);
    k_bscan<<<1, 256, 0, stream>>>(bcnt, gbase, gcur, nbuck, E);
    k_bucket<<<(E + 2047) / 2048, 256, 0, stream>>>(esrc, edst, gcur, pairs, E, nbuck);
    k_mid<<<nbuck + NPATH, 256, 0, stream>>>(
        pairs, gbase, sdst, base, pp, h, Wpath, bpath, index, aggbuf,
        N, E, nbuck, nrounds);
    k_spmm_out<<<(N + 3) / 4, 256, 0, stream>>>(Mb, base, sdst, aggbuf, bA, Wend, bend,
                                                (float*)d_out, N);
}

// Round 7
// 242.365 us; speedup vs baseline: 1.8498x; 1.1272x over previous
//
#include <hip/hip_runtime.h>
#include <hip/hip_bf16.h>
#include <math.h>

#define NF   128   // F
#define NPH  64    // PH
#define NP   8     // P
#define ND   4     // D
#define NH   128   // H
#define NC   10    // C

typedef __bf16 bf16;
typedef __attribute__((ext_vector_type(4))) __bf16 bf16x4;
typedef __attribute__((ext_vector_type(8))) __bf16 bf16x8;
typedef __attribute__((ext_vector_type(4))) float f32x4;

// DPP rotate-reduce within each 16-lane row: pure VALU, no LDS (replaces
// ds_bpermute-based __shfl_xor butterflies; ~4cy/step vs ~120cy).
template<int CTRL>
__device__ __forceinline__ float dpp_add(float x) {
    int t = __builtin_amdgcn_update_dpp(0, __float_as_int(x), CTRL, 0xf, 0xf, false);
    return x + __int_as_float(t);
}
__device__ __forceinline__ float row16_sum(float x) {
    x = dpp_add<0x121>(x);   // row_ror:1
    x = dpp_add<0x122>(x);   // row_ror:2
    x = dpp_add<0x124>(x);   // row_ror:4
    x = dpp_add<0x128>(x);   // row_ror:8
    return x;
}

// fast exact-erf GELU: Abramowitz-Stegun 7.1.25 (3-term), |eps|<=2.5e-5
__device__ __forceinline__ float gelu_fast(float x) {
    float z = fabsf(x) * 0.70710678118654752f;
    float t = __builtin_amdgcn_rcpf(1.0f + 0.47047f * z);
    float poly = t * (0.3480242f + t * (-0.0958798f + t * 0.7478556f));
    float erfv = 1.0f - poly * __expf(-z * z);
    float s = copysignf(erfv, x);
    return 0.5f * x * (1.0f + s);
}

#define GLOAD_LDS16(g, l)                                                     \
    __builtin_amdgcn_global_load_lds(                                         \
        (const __attribute__((address_space(1))) unsigned int*)(g),           \
        (__attribute__((address_space(3))) unsigned int*)(l), 16, 0, 0)

__device__ __forceinline__ bf16x8 cvt8(float4 a, float4 b) {
    bf16x8 r;
    r[0] = (bf16)a.x; r[1] = (bf16)a.y; r[2] = (bf16)a.z; r[3] = (bf16)a.w;
    r[4] = (bf16)b.x; r[5] = (bf16)b.y; r[6] = (bf16)b.z; r[7] = (bf16)b.w;
    return r;
}

// ---------------------------------------------------------------------------
// k_front: fused [proj | transpose | bhist] — mutually independent stages.
// ---------------------------------------------------------------------------
#define NBH 256   // bhist block count

__global__ __launch_bounds__(256) void k_front(
    const float* __restrict__ x,
    const float* __restrict__ Wproj, const float* __restrict__ bproj,
    const float* __restrict__ Wx,    const float* __restrict__ bx,
    bf16* __restrict__ pp, float* __restrict__ h,
    const float* __restrict__ WA, bf16* __restrict__ Mb,
    const int* __restrict__ esrc, int* __restrict__ bcnt,
    int N, int E, int nbuck, int nbP, int nbT)
{
    __shared__ alignas(16) char smem[33280];
    const int tid = threadIdx.x;
    const int bid = blockIdx.x;

    if (bid < nbP) {
        // ---------------- proj ----------------
        bf16* x_s = (bf16*)smem;                 // [64][136]
        const int w = tid >> 6, l = tid & 63;
        const int c = l & 15, g = l >> 4;

        bf16x8 bfr[3][4];
        float bias[3];
        #pragma unroll
        for (int t = 0; t < 3; ++t) {
            int ch = (w * 3 + t) * 16 + c;
            const float* wr = (ch < NPH) ? &Wproj[(size_t)ch * NF]
                                         : &Wx[(size_t)(ch - NPH) * NF];
            bias[t] = (ch < NPH) ? bproj[ch] : bx[ch - NPH];
            #pragma unroll
            for (int ks = 0; ks < 4; ++ks) {
                const float* src = wr + ks * 32 + g * 8;
                bfr[t][ks] = cvt8(*(const float4*)src, *(const float4*)(src + 4));
            }
        }

        const int n0 = bid * 64;
        #pragma unroll
        for (int rr = 0; rr < 8; ++rr) {
            int id  = rr * 256 + tid;        // 2048 float4 chunks: 64 rows x 32
            int row = id >> 5, c4 = id & 31;
            float4 v = make_float4(0.f, 0.f, 0.f, 0.f);
            if (n0 + row < N) v = *(const float4*)&x[(size_t)(n0 + row) * NF + c4 * 4];
            bf16x4 o;
            o[0] = (bf16)v.x; o[1] = (bf16)v.y; o[2] = (bf16)v.z; o[3] = (bf16)v.w;
            *(bf16x4*)&x_s[row * 136 + c4 * 4] = o;
        }
        __syncthreads();

        f32x4 acc[4][3] = {};
        #pragma unroll
        for (int rt = 0; rt < 4; ++rt)
            #pragma unroll
            for (int ks = 0; ks < 4; ++ks) {
                bf16x8 a = *(const bf16x8*)&x_s[(rt * 16 + c) * 136 + ks * 32 + g * 8];
                #pragma unroll
                for (int t = 0; t < 3; ++t)
                    acc[rt][t] = __builtin_amdgcn_mfma_f32_16x16x32_bf16(
                        a, bfr[t][ks], acc[rt][t], 0, 0, 0);
            }

        #pragma unroll
        for (int rt = 0; rt < 4; ++rt) {
            #pragma unroll
            for (int t = 0; t < 3; ++t) {
                int ch = (w * 3 + t) * 16 + c;
                #pragma unroll
                for (int i = 0; i < 4; ++i) {
                    int n = n0 + rt * 16 + g * 4 + i;
                    if (n >= N) continue;
                    float v = acc[rt][t][i] + bias[t];
                    if (ch < NPH) pp[(size_t)n * NPH + ch] = (bf16)v;
                    else          h[(size_t)n * NH + (ch - NPH)] = gelu_fast(v);
                }
            }
        }
    } else if (bid < nbP + nbT) {
        // ---------------- transpose ----------------
        float* tt = (float*)smem;                // [128][65]
        const int n0 = (bid - nbP) * 64;
        const int w = tid >> 6, l = tid & 63;
        #pragma unroll
        for (int rep = 0; rep < 32; ++rep) {
            int hh = rep * 4 + w;
            int n  = n0 + l;
            tt[hh * 65 + l] = (n < N) ? WA[(size_t)hh * N + n] : 0.f;
        }
        __syncthreads();
        #pragma unroll
        for (int rep = 0; rep < 32; ++rep) {
            int n_l = rep * 2 + (tid >> 7);
            int n   = n0 + n_l;
            if (n < N) Mb[(size_t)n * NH + (tid & 127)] = (bf16)tt[(tid & 127) * 65 + n_l];
        }
    } else {
        // ---------------- bhist ----------------
        int* hist = (int*)smem;
        hist[tid] = 0;
        __syncthreads();
        const int hb = bid - nbP - nbT;
        for (int i = hb * 256 + tid; i < E; i += NBH * 256)
            atomicAdd(&hist[esrc[i] >> 8], 1);
        __syncthreads();
        if (tid < nbuck && hist[tid])
            atomicAdd(&bcnt[tid], hist[tid]);
    }
}

// ---------------------------------------------------------------------------
__global__ __launch_bounds__(256) void k_bscan(
    const int* __restrict__ bcnt, int* __restrict__ gbase,
    int* __restrict__ gcur, int nbuck, int E)
{
    __shared__ int s[256];
    const int t = threadIdx.x;
    int v = (t < nbuck) ? bcnt[t] : 0;
    s[t] = v;
    __syncthreads();
    for (int off = 1; off < 256; off <<= 1) {
        int u = (t >= off) ? s[t - off] : 0;
        __syncthreads();
        s[t] += u;
        __syncthreads();
    }
    int ex = s[t] - v;
    if (t < nbuck) { gbase[t] = ex; gcur[t] = ex; }
    if (t == nbuck) gbase[t] = E;
}

__global__ __launch_bounds__(256) void k_bucket(
    const int* __restrict__ esrc, const int* __restrict__ edst,
    int* __restrict__ gcur, uint2* __restrict__ pairs, int E, int nbuck)
{
    __shared__ int cnt[256];
    __shared__ int bofs[256];
    const int tid = threadIdx.x;
    cnt[tid] = 0;
    __syncthreads();

    const int e0 = blockIdx.x * 2048;
    int src[8], dst[8], rk[8];
    #pragma unroll
    for (int k = 0; k < 8; ++k) {
        int i = e0 + k * 256 + tid;
        if (i < E) {
            src[k] = esrc[i]; dst[k] = edst[i];
            rk[k]  = atomicAdd(&cnt[src[k] >> 8], 1);
        } else src[k] = -1;
    }
    __syncthreads();
    if (tid < nbuck) {
        int cc = cnt[tid];
        bofs[tid] = cc ? atomicAdd(&gcur[tid], cc) : 0;
    }
    __syncthreads();
    #pragma unroll
    for (int k = 0; k < 8; ++k)
        if (src[k] >= 0)
            pairs[bofs[src[k] >> 8] + rk[k]] =
                make_uint2((unsigned)src[k], (unsigned)dst[k]);
}

// ---------------------------------------------------------------------------
// k_mid: fused [bsort | path].
// ---------------------------------------------------------------------------
__global__ __launch_bounds__(256) void k_mid(
    const uint2* __restrict__ pairs, const int* __restrict__ gbase,
    int* __restrict__ sdst, int* __restrict__ base,
    const bf16* __restrict__ pp, const float* __restrict__ h,
    const float* __restrict__ Wpath, const float* __restrict__ bpath,
    const int* __restrict__ index, float* __restrict__ aggbuf,
    int N, int E, int nbuck, int nrounds)
{
    __shared__ alignas(16) char smem[37376];
    const int tid = threadIdx.x;

    if (blockIdx.x < nbuck) {
        // ---------------- bsort ----------------
        int* hist = (int*)smem;
        int* sc   = hist + 256;
        int* cur  = hist + 512;
        const int b = blockIdx.x, t = tid;
        const int lo = gbase[b], hi = gbase[b + 1];
        hist[t] = 0;
        __syncthreads();
        for (int j = lo + t; j < hi; j += 256)
            atomicAdd(&hist[pairs[j].x & 255], 1);
        __syncthreads();
        int v = hist[t];
        sc[t] = v;
        __syncthreads();
        for (int off = 1; off < 256; off <<= 1) {
            int u = (t >= off) ? sc[t - off] : 0;
            __syncthreads();
            sc[t] += u;
            __syncthreads();
        }
        int ex = lo + sc[t] - v;
        cur[t] = ex;
        int n = b * 256 + t;
        if (n < N) base[n] = ex;
        if (b == 0 && t == 0) base[N] = E;
        __syncthreads();
        for (int j = lo + t; j < hi; j += 256) {
            uint2 p = pairs[j];
            int pos = atomicAdd(&cur[p.x & 255], 1);
            sdst[pos] = (int)p.y;
        }
        return;
    }

    // ---------------- path (round-4 structure) ----------------
    bf16*  path_s = (bf16*)smem;                 // [2][32*256]
    float* h_sf   = (float*)(smem + 32768);      // [2][4][128]
    float* s_red  = (float*)(smem + 36864);      // [4][32]

    const int w   = tid >> 6;
    const int l   = tid & 63;
    const int c   = l & 15;
    const int g   = l >> 4;
    const int nl  = g >> 1;            // local node (within a pair)

    // hoist B fragments (W_path cols for this wave's 2 h-tiles)
    bf16x8 bfrag[2][8];
    #pragma unroll
    for (int ht = 0; ht < 2; ++ht) {
        int hg = (w * 2 + ht) * 16 + c;
        #pragma unroll
        for (int ks = 0; ks < 8; ++ks) {
            const float* src = &Wpath[(size_t)hg * 256 + ks * 32 + g * 8];
            bfrag[ht][ks] = cvt8(*(const float4*)src, *(const float4*)(src + 4));
        }
    }
    const float bp0 = bpath[(w * 2 + 0) * 16 + c];
    const float bp1 = bpath[(w * 2 + 1) * 16 + c];

    auto stage = [&](int round, int b) {
        const int n0 = round * 4;
        #pragma unroll
        for (int rr = 0; rr < 4; ++rr) {
            int id  = rr * 256 + tid;
            int row = id >> 5;
            int cc  = id & 31;
            int ls  = cc ^ (row & 7);      // source-side swizzle
            int d   = ls >> 3, q = ls & 7;
            int nn  = row >> 3, p = row & 7;
            int idx = index[(size_t)(n0 + nn) * (NP * ND) + p * ND + d];
            GLOAD_LDS16(pp + (size_t)idx * NPH + q * 8, &path_s[b * 8192 + id * 8]);
        }
        if (tid < 128) {
            int node = tid >> 5, q = tid & 31;
            GLOAD_LDS16(&h[(size_t)(n0 + node) * NH + q * 4],
                        &h_sf[(b * 4 + node) * 128 + q * 4]);
        }
    };

    int r = blockIdx.x - nbuck;
    const int G = gridDim.x - nbuck;
    if (r < nrounds) stage(r, 0);
    int buf = 0;

    for (; r < nrounds; r += G) {
        const int n0 = r * 4;
        __syncthreads();                        // round-r stage complete
        if (r + G < nrounds) stage(r + G, buf ^ 1);   // prefetch next round

        // MFMA: row-tile rt covers rows rt*16..rt*16+15 (pair rt)
        f32x4 acc[2][2] = {};
        #pragma unroll
        for (int rt = 0; rt < 2; ++rt) {
            const int rowbase = buf * 8192 + (rt * 16 + c) * 256;
            #pragma unroll
            for (int ks = 0; ks < 8; ++ks) {
                int chunk = (ks * 4 + g) ^ (c & 7);     // read-side XOR
                bf16x8 a = *(const bf16x8*)&path_s[rowbase + chunk * 8];
                acc[rt][0] = __builtin_amdgcn_mfma_f32_16x16x32_bf16(
                    a, bfrag[0][ks], acc[rt][0], 0, 0, 0);
                acc[rt][1] = __builtin_amdgcn_mfma_f32_16x16x32_bf16(
                    a, bfrag[1][ks], acc[rt][1], 0, 0, 0);
            }
        }

        // epilogue part 1: pi = gelu(acc+b); row-sums via DPP (no LDS) -> s_red
        float pi[2][2][4];
        #pragma unroll
        for (int rt = 0; rt < 2; ++rt) {
            const float hv0 = h_sf[(buf * 4 + rt * 2 + nl) * 128 + w * 32 + c];
            const float hv1 = h_sf[(buf * 4 + rt * 2 + nl) * 128 + w * 32 + 16 + c];
            float sp[4];
            #pragma unroll
            for (int i = 0; i < 4; ++i) {
                pi[rt][0][i] = gelu_fast(acc[rt][0][i] + bp0);
                pi[rt][1][i] = gelu_fast(acc[rt][1][i] + bp1);
                sp[i] = hv0 * pi[rt][0][i] + hv1 * pi[rt][1][i];
            }
            #pragma unroll
            for (int i = 0; i < 4; ++i) sp[i] = row16_sum(sp[i]);
            float v = (c == 0) ? sp[0] : (c == 1) ? sp[1] : (c == 2) ? sp[2] : sp[3];
            if (c < 4) s_red[w * 32 + rt * 16 + g * 4 + c] = v;
        }

        // raw barrier: drain LDS ops only, keep global_load_lds in flight
        __builtin_amdgcn_sched_barrier(0);
        asm volatile("s_waitcnt lgkmcnt(0)" ::: "memory");
        __builtin_amdgcn_s_barrier();
        __builtin_amdgcn_sched_barrier(0);

        // epilogue part 2: softmax (vectorized s_red reads; broadcast-free)
        #pragma unroll
        for (int rt = 0; rt < 2; ++rt) {
            float4 r0 = *(const float4*)&s_red[0 * 32 + rt * 16 + g * 4];
            float4 r1 = *(const float4*)&s_red[1 * 32 + rt * 16 + g * 4];
            float4 r2 = *(const float4*)&s_red[2 * 32 + rt * 16 + g * 4];
            float4 r3 = *(const float4*)&s_red[3 * 32 + rt * 16 + g * 4];
            float st[4];
            st[0] = r0.x + r1.x + r2.x + r3.x;
            st[1] = r0.y + r1.y + r2.y + r3.y;
            st[2] = r0.z + r1.z + r2.z + r3.z;
            st[3] = r0.w + r1.w + r2.w + r3.w;
            float m4 = fmaxf(fmaxf(st[0], st[1]), fmaxf(st[2], st[3]));
            float m  = fmaxf(m4, __shfl_xor(m4, 16, 64));
            float e[4], s4 = 0.f;
            #pragma unroll
            for (int i = 0; i < 4; ++i) { e[i] = __expf(st[i] - m); s4 += e[i]; }
            float den = s4 + __shfl_xor(s4, 16, 64);
            const float inv = __builtin_amdgcn_rcpf(den);

            float pa0 = 0.f, pa1 = 0.f;
            #pragma unroll
            for (int i = 0; i < 4; ++i) {
                pa0 += e[i] * pi[rt][0][i];
                pa1 += e[i] * pi[rt][1][i];
            }
            pa0 = (pa0 + __shfl_xor(pa0, 16, 64)) * inv;
            pa1 = (pa1 + __shfl_xor(pa1, 16, 64)) * inv;

            if (!(g & 1)) {
                int n = n0 + rt * 2 + nl;
                const float hv0 = h_sf[(buf * 4 + rt * 2 + nl) * 128 + w * 32 + c];
                const float hv1 = h_sf[(buf * 4 + rt * 2 + nl) * 128 + w * 32 + 16 + c];
                aggbuf[(size_t)n * NH + w * 32 + c]      = 0.5f * (pa0 + hv0);
                aggbuf[(size_t)n * NH + w * 32 + 16 + c] = 0.5f * (pa1 + hv1);
            }
        }
        buf ^= 1;
    }
}

// ---------------------------------------------------------------------------
// K3: A_x row-gather + fused finale.
// ---------------------------------------------------------------------------
__device__ __forceinline__ void add8(float* a, uint4 v) {
    a[0] += __uint_as_float(v.x << 16);  a[1] += __uint_as_float(v.x & 0xffff0000u);
    a[2] += __uint_as_float(v.y << 16);  a[3] += __uint_as_float(v.y & 0xffff0000u);
    a[4] += __uint_as_float(v.z << 16);  a[5] += __uint_as_float(v.z & 0xffff0000u);
    a[6] += __uint_as_float(v.w << 16);  a[7] += __uint_as_float(v.w & 0xffff0000u);
}

__global__ __launch_bounds__(256) void k_spmm_out(
    const bf16* __restrict__ Mb, const int* __restrict__ base,
    const int* __restrict__ sdst, const float* __restrict__ aggbuf,
    const float* __restrict__ bA, const float* __restrict__ Wend,
    const float* __restrict__ bend, float* __restrict__ out, int N)
{
    __shared__ float wend_s[NC][128];
    __shared__ float bend_s[NC];
    const int tid = threadIdx.x;
    for (int id = tid; id < NC * 128; id += 256) wend_s[id >> 7][id & 127] = Wend[id];
    if (tid < NC) bend_s[tid] = bend[tid];
    __syncthreads();

    const int w = tid >> 6, l = tid & 63;
    const int n = blockIdx.x * 4 + w;
    if (n >= N) return;
    const int e = l >> 4, q = l & 15;
    const unsigned short* Mu = (const unsigned short*)Mb;

    const int b0 = base[n], b1 = base[n + 1];
    float acc[8] = {0.f, 0.f, 0.f, 0.f, 0.f, 0.f, 0.f, 0.f};
    int j = b0;
    for (; j + 32 <= b1; j += 32) {
        int d[8];
        #pragma unroll
        for (int k = 0; k < 8; ++k) d[k] = sdst[j + k * 4 + e];
        uint4 v[8];
        #pragma unroll
        for (int k = 0; k < 8; ++k)
            v[k] = *((const uint4*)(Mu + (size_t)d[k] * NH) + q);
        #pragma unroll
        for (int k = 0; k < 8; ++k) add8(acc, v[k]);
    }
    for (; j + 16 <= b1; j += 16) {
        int d[4];
        #pragma unroll
        for (int k = 0; k < 4; ++k) d[k] = sdst[j + k * 4 + e];
        uint4 v[4];
        #pragma unroll
        for (int k = 0; k < 4; ++k)
            v[k] = *((const uint4*)(Mu + (size_t)d[k] * NH) + q);
        #pragma unroll
        for (int k = 0; k < 4; ++k) add8(acc, v[k]);
    }
    for (; j + 4 <= b1; j += 4) {
        int d0 = sdst[j + e];
        uint4 v0 = *((const uint4*)(Mu + (size_t)d0 * NH) + q);
        add8(acc, v0);
    }
    if (e < b1 - j) {
        int d0 = sdst[j + e];
        uint4 v0 = *((const uint4*)(Mu + (size_t)d0 * NH) + q);
        add8(acc, v0);
    }
    #pragma unroll
    for (int k = 0; k < 8; ++k) {
        acc[k] += __shfl_xor(acc[k], 16, 64);
        acc[k] += __shfl_xor(acc[k], 32, 64);
    }

    // epilogue: all lanes (4x redundant across e-groups), lane owns ch q*8..+7
    float4 agA = *(const float4*)&aggbuf[(size_t)n * NH + q * 8];
    float4 agB = *(const float4*)&aggbuf[(size_t)n * NH + q * 8 + 4];
    float4 bA0 = *(const float4*)&bA[q * 8];
    float4 bA1 = *(const float4*)&bA[q * 8 + 4];
    float gg[8];
    gg[0] = gelu_fast(agA.x + 0.5f * (acc[0] + bA0.x));
    gg[1] = gelu_fast(agA.y + 0.5f * (acc[1] + bA0.y));
    gg[2] = gelu_fast(agA.z + 0.5f * (acc[2] + bA0.z));
    gg[3] = gelu_fast(agA.w + 0.5f * (acc[3] + bA0.w));
    gg[4] = gelu_fast(agB.x + 0.5f * (acc[4] + bA1.x));
    gg[5] = gelu_fast(agB.y + 0.5f * (acc[5] + bA1.y));
    gg[6] = gelu_fast(agB.z + 0.5f * (acc[6] + bA1.z));
    gg[7] = gelu_fast(agB.w + 0.5f * (acc[7] + bA1.w));

    float part[NC];
    #pragma unroll
    for (int cc = 0; cc < NC; ++cc) {
        float p = 0.f;
        #pragma unroll
        for (int k = 0; k < 8; ++k) p += gg[k] * wend_s[cc][q * 8 + k];
        part[cc] = row16_sum(p);     // DPP: within-16 reduce, no LDS
    }

    float r = part[0];
    #pragma unroll
    for (int cc = 1; cc < NC; ++cc) r = (l == cc) ? part[cc] : r;
    if (l < NC) out[(size_t)n * NC + l] = r + bend_s[l];
}

// ---------------------------------------------------------------------------
extern "C" void kernel_launch(void* const* d_in, const int* in_sizes, int n_in,
                              void* d_out, int out_size, void* d_ws, size_t ws_size,
                              hipStream_t stream)
{
    const float* x     = (const float*)d_in[0];
    const float* Wproj = (const float*)d_in[1];
    const float* bproj = (const float*)d_in[2];
    const float* Wx    = (const float*)d_in[3];
    const float* bx    = (const float*)d_in[4];
    const float* Wpath = (const float*)d_in[5];
    const float* bpath = (const float*)d_in[6];
    const float* WA    = (const float*)d_in[7];
    const float* bA    = (const float*)d_in[8];
    const float* Wend  = (const float*)d_in[9];
    const float* bend  = (const float*)d_in[10];
    const int*   index = (const int*)d_in[11];
    const int*   eidx  = (const int*)d_in[12];

    const int N = in_sizes[0] / NF;
    const int E = in_sizes[12] / 2;
    const int* esrc = eidx;
    const int* edst = eidx + E;
    const int nbuck = (N + 255) >> 8;

    char* p = (char*)d_ws;
    auto alloc = [&](size_t bytes) {
        char* r = p;
        p += (bytes + 255) & ~(size_t)255;
        return r;
    };
    bf16*  pp     = (bf16*)alloc((size_t)N * NPH * sizeof(bf16));
    float* h      = (float*)alloc((size_t)N * NH * sizeof(float));
    float* aggbuf = (float*)alloc((size_t)N * NH * sizeof(float));
    bf16*  Mb     = (bf16*)alloc((size_t)N * NH * sizeof(bf16));
    int*   base   = (int*)alloc((size_t)(N + 1) * sizeof(int));
    int*   sdst   = (int*)alloc((size_t)E * sizeof(int));
    int*   bcnt   = (int*)alloc(256 * sizeof(int));
    int*   gbase  = (int*)alloc(257 * sizeof(int));
    int*   gcur   = (int*)alloc(256 * sizeof(int));
    uint2* pairs  = (uint2*)alloc((size_t)E * sizeof(uint2));

    const int nbP = (N + 63) / 64;
    const int nbT = (N + 63) / 64;
    const int NPATH = 1024;
    const int nrounds = N / 4;

    hipMemsetAsync(bcnt, 0, 256 * sizeof(int), stream);
    k_front<<<nbP + nbT + NBH, 256, 0, stream>>>(
        x, Wproj, bproj, Wx, bx, pp, h, WA, Mb, esrc, bcnt, N, E, nbuck, nbP, nbT);
    k_bscan<<<1, 256, 0, stream>>>(bcnt, gbase, gcur, nbuck, E);
    k_bucket<<<(E + 2047) / 2048, 256, 0, stream>>>(esrc, edst, gcur, pairs, E, nbuck);
    k_mid<<<nbuck + NPATH, 256, 0, stream>>>(
        pairs, gbase, sdst, base, pp, h, Wpath, bpath, index, aggbuf,
        N, E, nbuck, nrounds);
    k_spmm_out<<<(N + 3) / 4, 256, 0, stream>>>(Mb, base, sdst, aggbuf, bA, Wend, bend,
                                                (float*)d_out, N);
}